// Round 8
// baseline (55.580 us; speedup 1.0000x reference)
//
#include <hip/hip_runtime.h>

#define NB 32
#define NH 720
#define NW 1280
#define NHW (NH * NW)        // 921600
#define NV4 (NHW / 4)        // 230400 float4 per image
#define KTOP 1024
#define CAP 2048             // per-image candidate cap (~830 expected)
#define BPI 60               // gather blocks per image (12 rows each)
#define V4PB (NV4 / BPI)     // 3840 float4 per block
#define NLD 15               // float4 loads per thread, all in flight
#define LCAP 48              // per-block candidate slots (expected ~14, +9 sigma)
#define NGB (NB * BPI)       // 1920 gather blocks
#define NZB 1920             // zero blocks

typedef float vf4 __attribute__((ext_vector_type(4)));   // native vector for nt-store

// ---- K1: block-role-split zero + gather (one dispatch, decoupled streams) ----
// Even blocks: LOAD-ONLY gather, all 15 float4 loads issued before any consume
// (progressive vmcnt drain -> near-pure streaming). Odd blocks: STORE-ONLY nt
// zero-fill. Candidates stage in LDS, flush to FIXED per-block slots (no
// global atomics, no prior memset).
__global__ __launch_bounds__(256)
void k_zero_gather(const float* __restrict__ prob,
                   const float* __restrict__ thr_p,
                   float* __restrict__ out,
                   int* __restrict__ cnt,
                   float2* __restrict__ cand) {
  const int b = blockIdx.x;

  if (b & 1) {
    // -------- zero role --------
    const int zb = b >> 1;
    vf4* __restrict__ out4 =
        reinterpret_cast<vf4*>(out) + (size_t)zb * V4PB + threadIdx.x;
    const vf4 z = {0.f, 0.f, 0.f, 0.f};
#pragma unroll
    for (int it = 0; it < NLD; ++it)
      __builtin_nontemporal_store(z, &out4[it * 256]);
    return;
  }

  // -------- gather role --------
  const int gblk = b >> 1;              // 0 .. NGB-1
  const int img = gblk / BPI;
  const int blk = gblk - img * BPI;
  const float thr = thr_p[0];

  __shared__ int lcount;
  __shared__ float2 lcand[LCAP];
  if (threadIdx.x == 0) lcount = 0;
  __syncthreads();

  const float4* __restrict__ in4 =
      reinterpret_cast<const float4*>(prob) + (size_t)img * NV4 + blk * V4PB + threadIdx.x;
  const int idx0 = (blk * V4PB + threadIdx.x) * 4;   // flat idx within image

  float4 p[NLD];
#pragma unroll
  for (int k = 0; k < NLD; ++k) p[k] = in4[k * 256];   // 15 loads in flight

#pragma unroll
  for (int k = 0; k < NLD; ++k) {
    const float4 v = p[k];
    const int base = idx0 + k * 1024;                  // k*256 float4 = k*1024 px
#define CHECKC(val, c)                                                   \
    if ((val) >= thr) {                                                  \
      const int pos = atomicAdd(&lcount, 1);                             \
      if (pos < LCAP)                                                    \
        lcand[pos] = make_float2((val), __int_as_float(base + (c)));     \
    }
    CHECKC(v.x, 0) CHECKC(v.y, 1) CHECKC(v.z, 2) CHECKC(v.w, 3)
#undef CHECKC
  }
  __syncthreads();

  const int ln = min(lcount, LCAP);
  if (threadIdx.x == 0) cnt[gblk] = ln;
  for (int i = threadIdx.x; i < ln; i += 256)
    cand[(size_t)gblk * LCAP + i] = lcand[i];
}

// plain zeroing (fallback path)
__global__ void k_zero_out(float* __restrict__ out) {
  const int total4 = NB * NV4;
  const int stride = gridDim.x * blockDim.x;
  const float4 z = make_float4(0.f, 0.f, 0.f, 0.f);
  for (int v = blockIdx.x * blockDim.x + threadIdx.x; v < total4; v += stride)
    reinterpret_cast<float4*>(out)[v] = z;
}

// ---- K2: chunk-neighborhood NMS (no row sort needed) ----
// Candidates compact chunk-contiguously (coff), chunk = 12 rows; conflicts
// (|dy| <= S-1 = 3) can only involve chunks c-1..c+1, so the conflict scan
// is a direct pass over those slots (~42). Conflicted subset (~27) is sorted
// by (score desc, idx asc) = exact top_k order; greedy over it == full greedy
// (isolated candidates can neither suppress nor be suppressed). Slow path
// (n > KTOP, never on this data): rank-filter to the exact top-K set, mark
// ALL conflicted -> F/G run full exact greedy.
__global__ __launch_bounds__(1024)
void k_nms(const int* __restrict__ size_p,
           const int* __restrict__ cnt,
           const float2* __restrict__ cand,
           float* __restrict__ out) {
  const int img = blockIdx.x;
  const int tid = threadIdx.x;
  const int lane = tid & 63;
  const int Si = size_p[0];           // box side (4)
  const int A2 = 2 * Si * Si;         // iou > 0.1  <=>  11*inter > A2 (exact ints)

  __shared__ int   px[KTOP];          // packed (y<<11)|x, slot order (chunk-grouped)
  __shared__ float sc[KTOP];          // score, slot order
  __shared__ short schunk[KTOP];      // slot -> chunk id
  __shared__ int   keep[KTOP];
  __shared__ int   clslot[KTOP];      // conflicted slots (arbitrary order)
  __shared__ int   cls2[KTOP];        // conflicted slots, priority order
  __shared__ int   coff[BPI + 1];     // chunk slot offsets
  __shared__ int   ncl_sh, nfill_sh;
  __shared__ float bsc[CAP];          // slow-path staging
  __shared__ int   bpx[CAP];

  keep[tid] = 1;
  if (tid == 0) { ncl_sh = 0; nfill_sh = 0; }

  // ---- A0: scan the 60 chunk counts (wave 0, no barrier inside) ----
  if (tid < 64) {
    int s = (tid < BPI) ? cnt[img * BPI + tid] : 0;
#pragma unroll
    for (int d = 1; d < 64; d <<= 1) {
      const int u = __shfl_up(s, d, 64);
      if (lane >= d) s += u;
    }
    if (tid < BPI) coff[tid + 1] = s;
    if (tid == 0) coff[0] = 0;
  }
  __syncthreads();
  const int n1all = coff[BPI];
  const int n1 = min(n1all, CAP);
  const int neff = min(n1, KTOP);
  const bool fast = (n1all <= KTOP);

  // ---- A1: compact chunks into slot arrays ----
  if (fast) {
    for (int t = tid; t < BPI * LCAP; t += 1024) {
      const int chunk = t / LCAP;
      const int i = t - chunk * LCAP;
      const int base = coff[chunk];
      if (i < coff[chunk + 1] - base) {
        const float2 e2 = cand[(size_t)(img * BPI + chunk) * LCAP + i];
        const int e = __float_as_int(e2.y);
        const int y = e / NW;
        px[base + i] = (y << 11) | (e - y * NW);
        sc[base + i] = e2.x;
        schunk[base + i] = (short)chunk;
      }
    }
    __syncthreads();
  } else {
    // slow path: stage all, rank-filter to the exact top-KTOP set
    for (int t = tid; t < BPI * LCAP; t += 1024) {
      const int chunk = t / LCAP;
      const int i = t - chunk * LCAP;
      const int base = coff[chunk];
      if (i < coff[chunk + 1] - base && base + i < CAP) {
        const float2 e2 = cand[(size_t)(img * BPI + chunk) * LCAP + i];
        const int e = __float_as_int(e2.y);
        const int y = e / NW;
        bpx[base + i] = (y << 11) | (e - y * NW);
        bsc[base + i] = e2.x;
      }
    }
    __syncthreads();
    for (int t = tid; t < n1; t += 1024) {
      const float s = bsc[t];
      const int p = bpx[t];
      const int gidx = (p >> 11) * NW + (p & 2047);
      int r = 0;
      for (int i = 0; i < n1; ++i) {
        const float os = bsc[i];
        const int op = bpx[i];
        const int oidx = (op >> 11) * NW + (op & 2047);
        r += (os > s) || (os == s && oidx < gidx);
      }
      if (r < KTOP) {
        const int w = atomicAdd(&nfill_sh, 1);
        px[w] = p;
        sc[w] = s;
      }
    }
    __syncthreads();
  }

  // ---- E: conflict scan over chunks c-1..c+1 (fast) / mark all (slow) ----
  if (fast) {
    if (tid < neff) {
      const int p = px[tid];
      const int y = p >> 11, x = p & 2047;
      const int c = schunk[tid];
      const int lo = coff[max(c - 1, 0)];
      const int hi = coff[min(c + 2, BPI)];
      int conf = 0;
      for (int q = lo; q < hi; ++q) {
        if (q == tid) continue;
        const int op = px[q];
        const int iy = Si - abs(y - (op >> 11));
        const int ix = Si - abs(x - (op & 2047));
        conf |= (iy > 0) & (ix > 0) & (11 * iy * ix > A2);
      }
      if (conf) {
        const int w = atomicAdd(&ncl_sh, 1);
        clslot[w] = tid;
      }
    }
  } else {
    if (tid < neff) clslot[tid] = tid;
    if (tid == 0) ncl_sh = neff;
  }
  __syncthreads();
  const int k = ncl_sh;

  // ---- F: sort conflicted subset by (score desc, idx asc) ----
  if (tid < k) {
    const int myslot = clslot[tid];
    const float ms = sc[myslot];
    const int mp = px[myslot];
    const int midx = (mp >> 11) * NW + (mp & 2047);
    int r = 0;
    for (int b2 = 0; b2 < k; ++b2) {
      const int os_l = clslot[b2];
      const float os = sc[os_l];
      const int op = px[os_l];
      const int oidx = (op >> 11) * NW + (op & 2047);
      r += (os > ms) || (os == ms && oidx < midx);
    }
    cls2[r] = myslot;
  }
  __syncthreads();

  // ---- G: exact greedy over conflicted subset ----
  if (k <= 64) {
    // register-resident: lane a holds candidate a; broadcast via shfl.
    if (tid < 64) {
      const int slot = (tid < k) ? cls2[tid] : -1;
      const int p = (slot >= 0) ? px[slot] : 0;
      const int y = p >> 11, x = p & 2047;
      int keep_l = 1;
      for (int a = 1; a < k; ++a) {
        const int ya = __shfl(y, a, 64);
        const int xa = __shfl(x, a, 64);
        const int iy = Si - abs(ya - y);
        const int ix = Si - abs(xa - x);
        const bool hit = (tid < a) && keep_l && (iy > 0) && (ix > 0) &&
                         (11 * iy * ix > A2);
        const bool sup = __any(hit);
        if (tid == a && sup) keep_l = 0;
      }
      if (tid < k && !keep_l) keep[slot] = 0;
    }
  } else if (tid < 64) {
    // LDS fallback (k > 64): full greedy in priority order (exact)
    for (int a = 1; a < k; ++a) {
      const int j = cls2[a];
      const int pj = px[j];
      const int yj = pj >> 11, xj = pj & 2047;
      bool sup = false;
      for (int base = 0; base < a; base += 64) {
        const int b2 = base + tid;
        bool hit = false;
        if (b2 < a) {
          const int i2 = cls2[b2];
          if (keep[i2]) {
            const int op = px[i2];
            const int iy = Si - abs(yj - (op >> 11));
            const int ix = Si - abs(xj - (op & 2047));
            hit = (iy > 0) && (ix > 0) && (11 * iy * ix > A2);
          }
        }
        if (__any(hit)) { sup = true; break; }
      }
      if (tid == 0 && sup) keep[j] = 0;
    }
  }
  __syncthreads();

  // ---- H: scatter kept scores ----
  if (tid < neff && keep[tid]) {
    const int p = px[tid];
    out[(size_t)img * NHW + (p >> 11) * NW + (p & 2047)] = sc[tid];
  }
}

// --------- fallback: monolithic per-image kernel (no workspace) ---------
__global__ __launch_bounds__(1024)
void k_nms_mono(const float* __restrict__ prob,
                const float* __restrict__ thr_p,
                const int* __restrict__ size_p,
                float* __restrict__ out) {
  const int img = blockIdx.x;
  const int tid = threadIdx.x;
  const float thr = thr_p[0];
  const float S = (float)size_p[0];
  const float A = 2.f * S * S;
  const float* ip = prob + (size_t)img * NHW;

  __shared__ float sc[CAP];
  __shared__ int   gi[CAP];
  __shared__ float ssc[KTOP];
  __shared__ int   sgi[KTOP];
  __shared__ int   keepf[KTOP];
  __shared__ int   sh_n;

  if (tid == 0) sh_n = 0;
  __syncthreads();
  for (int e = tid; e < NHW; e += 1024) {
    const float p = ip[e];
    if (p >= thr) {
      const int pos = atomicAdd(&sh_n, 1);
      if (pos < CAP) { sc[pos] = p; gi[pos] = e; }
    }
  }
  __syncthreads();
  const int n = min(sh_n, CAP);
  const int m = min(n, KTOP);

  for (int j = tid; j < n; j += 1024) {
    const float sj = sc[j]; const int gj = gi[j];
    int r = 0;
    for (int i = 0; i < n; ++i)
      r += (sc[i] > sj) || (sc[i] == sj && gi[i] < gj);
    if (r < KTOP) { ssc[r] = sj; sgi[r] = gj; }
  }
  keepf[tid] = (tid < m);
  __syncthreads();

  for (int i = 0; i < m; ++i) {
    __syncthreads();
    if (!keepf[i]) continue;
    const int g = sgi[i];
    const int yi0 = g / NW;
    const float yi = (float)yi0, xi = (float)(g - yi0 * NW);
    if (tid > i && tid < m && keepf[tid]) {
      const int g2 = sgi[tid];
      const int yj0 = g2 / NW;
      const float iy = S - fabsf(yi - (float)yj0);
      const float ix = S - fabsf(xi - (float)(g2 - yj0 * NW));
      if (fminf(iy, ix) > 0.f && 11.f * iy * ix > A) keepf[tid] = 0;
    }
  }
  __syncthreads();
  if (tid < m && keepf[tid])
    out[(size_t)img * NHW + sgi[tid]] = ssc[tid];
}

extern "C" void kernel_launch(void* const* d_in, const int* in_sizes, int n_in,
                              void* d_out, int out_size, void* d_ws, size_t ws_size,
                              hipStream_t stream) {
  const float* prob   = (const float*)d_in[0];
  const int*   size_p = (const int*)d_in[1];
  const float* thr_p  = (const float*)d_in[2];
  float* out = (float*)d_out;

  const size_t cnt_b  = (size_t)NGB * sizeof(int);            // 7.7 KB
  const size_t cand_b = (size_t)NGB * LCAP * sizeof(float2);  // 737 KB
  const size_t needed = cnt_b + cand_b;                       // ~745 KB

  if (ws_size >= needed) {
    int*    cnt  = (int*)d_ws;
    float2* cand = (float2*)((char*)d_ws + cnt_b);
    k_zero_gather<<<NGB + NZB, 256, 0, stream>>>(prob, thr_p, out, cnt, cand);
    k_nms<<<NB, KTOP, 0, stream>>>(size_p, cnt, cand, out);
  } else {
    k_zero_out<<<2048, 256, 0, stream>>>(out);
    k_nms_mono<<<NB, 1024, 0, stream>>>(prob, thr_p, size_p, out);
  }
}